// Round 8
// baseline (424.751 us; speedup 1.0000x reference)
//
#include <hip/hip_runtime.h>

typedef __bf16 bf16x8 __attribute__((ext_vector_type(8)));
typedef __bf16 bf16x4 __attribute__((ext_vector_type(4)));
typedef float f32x4 __attribute__((ext_vector_type(4)));

#define LN_EPS 1e-5f

// async global->LDS, 16B per lane (HW: wave-uniform LDS base + lane*16)
__device__ __forceinline__ void gl2lds16(const void* g, void* l) {
  __builtin_amdgcn_global_load_lds(
      (const __attribute__((address_space(1))) unsigned int*)g,
      (__attribute__((address_space(3))) unsigned int*)l, 16, 0, 0);
}

// -------- weight transpose + downcast: in f32 [R][C] -> out bf16 [C][R] --------
__global__ __launch_bounds__(256) void transpose_k(const float* __restrict__ in,
                                                   __bf16* __restrict__ out,
                                                   int R, int C) {
  __shared__ __bf16 t[32][33];
  int tx = threadIdx.x & 31, ty = threadIdx.x >> 5;  // 32x8
  int c = blockIdx.x * 32 + tx;
  for (int j = 0; j < 4; j++) {
    int r = blockIdx.y * 32 + ty + j * 8;
    t[ty + j * 8][tx] = (__bf16)in[(size_t)r * C + c];
  }
  __syncthreads();
  int r2 = blockIdx.y * 32 + tx;
  for (int j = 0; j < 4; j++) {
    int c2 = blockIdx.x * 32 + ty + j * 8;
    out[(size_t)c2 * R + r2] = t[tx][ty + j * 8];
  }
}

// -------- V transpose: qkv[token][2304] V-part -> vt[(b*12+h)*64+d][2048] --------
__global__ __launch_bounds__(256) void transpose_v(const __bf16* __restrict__ qkv,
                                                   __bf16* __restrict__ vt) {
  __shared__ __bf16 t[32][33];
  int bh = blockIdx.z;
  int b = bh / 12, h = bh % 12;
  int n0 = blockIdx.x * 32, d0 = blockIdx.y * 32;
  int tx = threadIdx.x & 31, ty = threadIdx.x >> 5;
  for (int j = 0; j < 4; j++) {
    int n = n0 + ty + j * 8;
    t[ty + j * 8][tx] = qkv[(size_t)(b * 2048 + n) * 2304 + 1536 + h * 64 + d0 + tx];
  }
  __syncthreads();
  for (int j = 0; j < 4; j++) {
    int d = d0 + ty + j * 8;
    vt[((size_t)bh * 64 + d) * 2048 + n0 + tx] = t[tx][ty + j * 8];
  }
}

// -------- layernorm over 768: f32 in -> bf16 out, one block per row --------
__global__ __launch_bounds__(256) void ln_kernel(const float* __restrict__ x,
                                                 const float* __restrict__ g,
                                                 const float* __restrict__ bta,
                                                 __bf16* __restrict__ out) {
  int row = blockIdx.x;
  size_t base = (size_t)row * 768;
  int t = threadIdx.x;
  float v[3];
  float s = 0.f, s2 = 0.f;
  for (int k = 0; k < 3; k++) {
    float f = x[base + t + k * 256];
    v[k] = f;
    s += f;
    s2 += f * f;
  }
  for (int m = 1; m < 64; m <<= 1) {
    s += __shfl_xor(s, m, 64);
    s2 += __shfl_xor(s2, m, 64);
  }
  __shared__ float sm[4][2];
  int wid = t >> 6, lane = t & 63;
  if (lane == 0) { sm[wid][0] = s; sm[wid][1] = s2; }
  __syncthreads();
  s = sm[0][0] + sm[1][0] + sm[2][0] + sm[3][0];
  s2 = sm[0][1] + sm[1][1] + sm[2][1] + sm[3][1];
  float mu = s * (1.f / 768.f);
  float var = s2 * (1.f / 768.f) - mu * mu;
  float rstd = rsqrtf(var + LN_EPS);
  for (int k = 0; k < 3; k++) {
    int c = t + k * 256;
    out[base + c] = (__bf16)((v[k] - mu) * rstd * g[c] + bta[c]);
  }
}

// -------- double-buffered MFMA GEMM, BK=32, one barrier per iter --------
// C[M,N] = A[M,K] @ BT[N,K]^T + bias. Tile MT x NT (2x2 waves).
// EPI 0: bf16 out = c ; EPI 1: bf16 poly-gelu ; EPI 2: f32 out = c + res
template <int MT, int NT, int EPI>
__global__ __launch_bounds__(256, 4)
void gemm_db(const __bf16* __restrict__ A, const __bf16* __restrict__ BT,
             const float* __restrict__ bias, const float* __restrict__ res,
             void* __restrict__ outv, int M, int N, int K,
             const float* __restrict__ c0p, const float* __restrict__ c1p,
             const float* __restrict__ c2p) {
  // unpadded 64B rows for glds; 16B chunks XOR-swizzled by (row&3):
  // fragment b128 reads land 2-way on banks (free) instead of 8-way.
  __shared__ __bf16 As[2][MT][32];
  __shared__ __bf16 Bs[2][NT][32];
  constexpr int IW = MT / 32, JW = NT / 32;
  const int tid = threadIdx.x, lane = tid & 63, wid = tid >> 6;
  const int wr = wid >> 1, wc = wid & 1;
  const int mr = lane & 15, quad = lane >> 4;
  const int m0 = blockIdx.y * MT, n0 = blockIdx.x * NT;
  const int swzsrc = (((lane & 3) ^ ((lane >> 2) & 3)) * 8);  // source chunk (elems)
  const int srow = lane >> 2;                                  // 16 rows per wave-issue
  const int ck = ((quad ^ (mr & 3)) * 8);                      // fragment chunk (elems)

  f32x4 acc[IW][JW] = {};

  auto stage = [&](int k0, int pb) {
    for (int g = 0; g < MT / 64; g++) {
      int r0 = wid * (MT / 4) + g * 16 + srow;
      gl2lds16(&A[(size_t)(m0 + r0) * K + k0 + swzsrc], &As[pb][r0][(lane & 3) * 8]);
    }
    for (int g = 0; g < NT / 64; g++) {
      int r0 = wid * (NT / 4) + g * 16 + srow;
      gl2lds16(&BT[(size_t)(n0 + r0) * K + k0 + swzsrc], &Bs[pb][r0][(lane & 3) * 8]);
    }
  };

  stage(0, 0);
  int pb = 0;
  for (int k0 = 0; k0 < K; k0 += 32) {
    __syncthreads();                          // drains prefetch; WAR for pb^1
    if (k0 + 32 < K) stage(k0 + 32, pb ^ 1);  // a full compute phase in flight
    bf16x8 af[IW], bfr[JW];
    for (int i = 0; i < IW; i++) af[i] = *(bf16x8*)&As[pb][wr * (MT / 2) + i * 16 + mr][ck];
    for (int j = 0; j < JW; j++) bfr[j] = *(bf16x8*)&Bs[pb][wc * (NT / 2) + j * 16 + mr][ck];
    for (int i = 0; i < IW; i++)
      for (int j = 0; j < JW; j++)
        acc[i][j] = __builtin_amdgcn_mfma_f32_16x16x32_bf16(af[i], bfr[j], acc[i][j], 0, 0, 0);
    pb ^= 1;
  }

  float ga = 0.f, gb = 0.f, gc = 0.f;
  if (EPI == 1) { ga = *c0p; gb = *c1p; gc = *c2p; }

  for (int i = 0; i < IW; i++) {
    for (int j = 0; j < JW; j++) {
      int col = n0 + wc * (NT / 2) + j * 16 + mr;
      float bv = bias[col];
      for (int r = 0; r < 4; r++) {
        int row = m0 + wr * (MT / 2) + i * 16 + quad * 4 + r;
        size_t idx = (size_t)row * N + col;
        float c = acc[i][j][r] + bv;
        if (EPI == 0) {
          ((__bf16*)outv)[idx] = (__bf16)c;
        } else if (EPI == 1) {
          float u = (ga * c + gb) * c + gc;
          ((__bf16*)outv)[idx] = (__bf16)u;
        } else {
          ((float*)outv)[idx] = c + res[idx];
        }
      }
    }
  }
}

// -------- flash-style polynomial attention (R7 structure, unchanged) --------
__global__ __launch_bounds__(256, 3) void attn_poly(const __bf16* __restrict__ qkv,
                                                    const __bf16* __restrict__ vt,
                                                    __bf16* __restrict__ outp,
                                                    const float* __restrict__ ap,
                                                    const float* __restrict__ bp,
                                                    const float* __restrict__ cp) {
  __shared__ __bf16 Ps[4][32][72];   // 18,432 B (per-wave regions, padded)
  __shared__ __bf16 Kb[2][64][64];   // 16,384 B (unpadded, swizzled chunks)
  __shared__ __bf16 Vb[2][64][64];   // 16,384 B

  const int tid = threadIdx.x, lane = tid & 63, wid = tid >> 6;
  const int mr = lane & 15, quad = lane >> 4;
  const int q0 = blockIdx.x * 128;
  const int h = blockIdx.y, b = blockIdx.z;
  const int bh = b * 12 + h;
  const size_t baseQ = ((size_t)b * 2048) * 2304 + h * 64;

  const int swzsrc = (((lane & 7) ^ ((lane >> 3) & 7)) * 8);
  const int srow8 = lane >> 3;
  const int colS0 = ((quad ^ (mr & 7)) * 8);        // s=0 fragment chunk
  const int colS1 = (((4 + quad) ^ (mr & 7)) * 8);  // s=1

  bf16x8 qf[2][2];
  for (int i = 0; i < 2; i++)
    for (int s = 0; s < 2; s++)
      qf[i][s] = *(const bf16x8*)&qkv[baseQ + (size_t)(q0 + wid * 32 + i * 16 + mr) * 2304 +
                                      s * 32 + quad * 8];

  const float a2 = (*ap) * 0.015625f, b2 = (*bp) * 0.125f, cc = *cp;  // SCALE folded
  f32x4 o_acc[2][4] = {};
  float l_acc[2] = {0.f, 0.f};

  auto stage = [&](int kt, int pb) {
    for (int g = 0; g < 2; g++) {
      int r0 = wid * 16 + g * 8 + srow8;
      gl2lds16(&qkv[baseQ + (size_t)(kt * 64 + r0) * 2304 + 768 + swzsrc],
               &Kb[pb][r0][(lane & 7) * 8]);
      gl2lds16(&vt[((size_t)bh * 64 + r0) * 2048 + kt * 64 + swzsrc],
               &Vb[pb][r0][(lane & 7) * 8]);
    }
  };

  stage(0, 0);
  int pb = 0;
  for (int kt = 0; kt < 32; kt++) {
    __syncthreads();
    if (kt < 31) stage(kt + 1, pb ^ 1);

    f32x4 sacc[2][4] = {};
    for (int j = 0; j < 4; j++) {
      for (int s = 0; s < 2; s++) {
        bf16x8 kf = *(bf16x8*)&Kb[pb][j * 16 + mr][s ? colS1 : colS0];
        for (int i = 0; i < 2; i++)
          sacc[i][j] = __builtin_amdgcn_mfma_f32_16x16x32_bf16(kf, qf[i][s], sacc[i][j], 0, 0, 0);
      }
    }
    for (int i = 0; i < 2; i++) {
      f32x4 racc = {0.f, 0.f, 0.f, 0.f};
      for (int j = 0; j < 4; j++) {
        f32x4 S = sacc[i][j];
        f32x4 p = (a2 * S + b2) * S + cc;
        p[0] = fmaxf(p[0], 1e-6f); p[1] = fmaxf(p[1], 1e-6f);
        p[2] = fmaxf(p[2], 1e-6f); p[3] = fmaxf(p[3], 1e-6f);
        racc += p;
        bf16x4 pk = {(__bf16)p[0], (__bf16)p[1], (__bf16)p[2], (__bf16)p[3]};
        *(bf16x4*)&Ps[wid][i * 16 + mr][j * 16 + quad * 4] = pk;
      }
      float rsum = racc[0] + racc[1] + racc[2] + racc[3];
      rsum += __shfl_xor(rsum, 16, 64);
      rsum += __shfl_xor(rsum, 32, 64);
      l_acc[i] += rsum;
    }

    __asm__ __volatile__("s_waitcnt lgkmcnt(0)" ::: "memory");

    for (int s = 0; s < 2; s++) {
      bf16x8 pf[2];
      for (int i = 0; i < 2; i++)
        pf[i] = *(bf16x8*)&Ps[wid][i * 16 + mr][s * 32 + quad * 8];
      for (int dt = 0; dt < 4; dt++) {
        bf16x8 vf = *(bf16x8*)&Vb[pb][dt * 16 + mr][s ? colS1 : colS0];
        for (int i = 0; i < 2; i++)
          o_acc[i][dt] = __builtin_amdgcn_mfma_f32_16x16x32_bf16(pf[i], vf, o_acc[i][dt], 0, 0, 0);
      }
    }
    __asm__ __volatile__("" ::: "memory");
    pb ^= 1;
  }

  size_t baseO = ((size_t)b * 2048) * 768 + h * 64;
  for (int i = 0; i < 2; i++) {
    float inv[4];
    for (int r = 0; r < 4; r++)
      inv[r] = 1.0f / (__shfl(l_acc[i], quad * 4 + r, 64) + 1e-8f);
    for (int dt = 0; dt < 4; dt++) {
      int q = q0 + wid * 32 + i * 16 + quad * 4;
      for (int r = 0; r < 4; r++)
        outp[baseO + (size_t)(q + r) * 768 + dt * 16 + mr] =
            (__bf16)(o_acc[i][dt][r] * inv[r]);
    }
  }
}

extern "C" void kernel_launch(void* const* d_in, const int* in_sizes, int n_in,
                              void* d_out, int out_size, void* d_ws, size_t ws_size,
                              hipStream_t stream) {
  const float* x     = (const float*)d_in[0];
  const float* ln1g  = (const float*)d_in[1];
  const float* ln1b  = (const float*)d_in[2];
  const float* ln2g  = (const float*)d_in[3];
  const float* ln2b  = (const float*)d_in[4];
  const float* qkvw  = (const float*)d_in[5];
  const float* qkvb  = (const float*)d_in[6];
  const float* projw = (const float*)d_in[7];
  const float* projb = (const float*)d_in[8];
  const float* fc1w  = (const float*)d_in[9];
  const float* fc1b  = (const float*)d_in[10];
  const float* fc2w  = (const float*)d_in[11];
  const float* fc2b  = (const float*)d_in[12];
  const float* attna = (const float*)d_in[13];
  const float* attnb = (const float*)d_in[14];
  const float* attnc = (const float*)d_in[15];
  const float* gelua = (const float*)d_in[16];
  const float* gelub = (const float*)d_in[17];
  const float* geluc = (const float*)d_in[18];

  char* ws = (char*)d_ws;
  __bf16* wT_qkv  = (__bf16*)(ws);             // [2304][768]  3,538,944 B
  __bf16* wT_proj = (__bf16*)(ws + 3538944);   // [768][768]   1,179,648 B
  __bf16* wT_fc1  = (__bf16*)(ws + 4718592);   // [3072][768]  4,718,592 B
  __bf16* wT_fc2  = (__bf16*)(ws + 9437184);   // [768][3072]  4,718,592 B
  __bf16* h       = (__bf16*)(ws + 14155776);  // [8192][768]  bf16 12,582,912 B
  float*  x1      = (float*)(ws + 26738688);   // [8192][768]  f32  25,165,824 B
  __bf16* qkvbuf  = (__bf16*)(ws + 51904512);  // [8192][2304] bf16 (dead after attn)
  __bf16* u       = (__bf16*)(ws + 51904512);  // [8192][3072] bf16 (overlaps qkv)
  __bf16* vtbuf   = (__bf16*)(ws + 89653248);  // [3072][2048] bf16 12,582,912 B
  float*  outp    = (float*)d_out;

  transpose_k<<<dim3(2304 / 32, 768 / 32), 256, 0, stream>>>(qkvw, wT_qkv, 768, 2304);
  transpose_k<<<dim3(768 / 32, 768 / 32), 256, 0, stream>>>(projw, wT_proj, 768, 768);
  transpose_k<<<dim3(3072 / 32, 768 / 32), 256, 0, stream>>>(fc1w, wT_fc1, 768, 3072);
  transpose_k<<<dim3(768 / 32, 3072 / 32), 256, 0, stream>>>(fc2w, wT_fc2, 3072, 768);

  ln_kernel<<<8192, 256, 0, stream>>>(x, ln1g, ln1b, h);
  gemm_db<128, 128, 0><<<dim3(18, 64), 256, 0, stream>>>(h, wT_qkv, qkvb, nullptr, qkvbuf,
                                                         8192, 2304, 768, nullptr, nullptr, nullptr);
  transpose_v<<<dim3(64, 2, 48), 256, 0, stream>>>(qkvbuf, vtbuf);
  attn_poly<<<dim3(16, 12, 4), 256, 0, stream>>>(qkvbuf, vtbuf, h, attna, attnb, attnc);
  gemm_db<64, 128, 2><<<dim3(6, 128), 256, 0, stream>>>(h, wT_proj, projb, x, x1,
                                                        8192, 768, 768, nullptr, nullptr, nullptr);
  ln_kernel<<<8192, 256, 0, stream>>>(x1, ln2g, ln2b, h);
  gemm_db<128, 128, 1><<<dim3(24, 64), 256, 0, stream>>>(h, wT_fc1, fc1b, nullptr, u,
                                                         8192, 3072, 768, gelua, gelub, geluc);
  gemm_db<64, 128, 2><<<dim3(6, 128), 256, 0, stream>>>(u, wT_fc2, fc2b, x1, outp,
                                                        8192, 768, 3072, nullptr, nullptr, nullptr);
}

// Round 9
// 402.628 us; speedup vs baseline: 1.0549x; 1.0549x over previous
//
#include <hip/hip_runtime.h>

typedef __bf16 bf16x8 __attribute__((ext_vector_type(8)));
typedef __bf16 bf16x4 __attribute__((ext_vector_type(4)));
typedef float f32x4 __attribute__((ext_vector_type(4)));

#define LN_EPS 1e-5f

// async global->LDS, 16B per lane (HW: wave-uniform LDS base + lane*16)
__device__ __forceinline__ void gl2lds16(const void* g, void* l) {
  __builtin_amdgcn_global_load_lds(
      (const __attribute__((address_space(1))) unsigned int*)g,
      (__attribute__((address_space(3))) unsigned int*)l, 16, 0, 0);
}

// pipeline barrier: wait only the oldest in-flight stage (KEEP loads stay
// outstanding across the barrier), then s_barrier. KEEP=0 == full drain.
template <int KEEP>
__device__ __forceinline__ void pipe_barrier() {
  if constexpr (KEEP == 0)
    __asm__ __volatile__("s_waitcnt vmcnt(0) lgkmcnt(0)\n\ts_barrier" ::: "memory");
  else if constexpr (KEEP == 3)
    __asm__ __volatile__("s_waitcnt vmcnt(3) lgkmcnt(0)\n\ts_barrier" ::: "memory");
  else if constexpr (KEEP == 4)
    __asm__ __volatile__("s_waitcnt vmcnt(4) lgkmcnt(0)\n\ts_barrier" ::: "memory");
}

// -------- weight transpose + downcast: in f32 [R][C] -> out bf16 [C][R] --------
__global__ __launch_bounds__(256) void transpose_k(const float* __restrict__ in,
                                                   __bf16* __restrict__ out,
                                                   int R, int C) {
  __shared__ __bf16 t[32][33];
  int tx = threadIdx.x & 31, ty = threadIdx.x >> 5;  // 32x8
  int c = blockIdx.x * 32 + tx;
  for (int j = 0; j < 4; j++) {
    int r = blockIdx.y * 32 + ty + j * 8;
    t[ty + j * 8][tx] = (__bf16)in[(size_t)r * C + c];
  }
  __syncthreads();
  int r2 = blockIdx.y * 32 + tx;
  for (int j = 0; j < 4; j++) {
    int c2 = blockIdx.x * 32 + ty + j * 8;
    out[(size_t)c2 * R + r2] = t[tx][ty + j * 8];
  }
}

// -------- layernorm over 768: f32 in -> bf16 out, one block per row --------
__global__ __launch_bounds__(256) void ln_kernel(const float* __restrict__ x,
                                                 const float* __restrict__ g,
                                                 const float* __restrict__ bta,
                                                 __bf16* __restrict__ out) {
  int row = blockIdx.x;
  size_t base = (size_t)row * 768;
  int t = threadIdx.x;
  float v[3];
  float s = 0.f, s2 = 0.f;
  for (int k = 0; k < 3; k++) {
    float f = x[base + t + k * 256];
    v[k] = f;
    s += f;
    s2 += f * f;
  }
  for (int m = 1; m < 64; m <<= 1) {
    s += __shfl_xor(s, m, 64);
    s2 += __shfl_xor(s2, m, 64);
  }
  __shared__ float sm[4][2];
  int wid = t >> 6, lane = t & 63;
  if (lane == 0) { sm[wid][0] = s; sm[wid][1] = s2; }
  __syncthreads();
  s = sm[0][0] + sm[1][0] + sm[2][0] + sm[3][0];
  s2 = sm[0][1] + sm[1][1] + sm[2][1] + sm[3][1];
  float mu = s * (1.f / 768.f);
  float var = s2 * (1.f / 768.f) - mu * mu;
  float rstd = rsqrtf(var + LN_EPS);
  for (int k = 0; k < 3; k++) {
    int c = t + k * 256;
    out[base + c] = (__bf16)((v[k] - mu) * rstd * g[c] + bta[c]);
  }
}

// -------- pipelined MFMA GEMM: triple-buffer glds, vmcnt(S) barrier --------
// C[M,N] = A[M,K] @ BT[N,K]^T + bias. Tile MT x NT (2x2 waves), BK=32.
// EPI 1: bf16 poly-gelu ; EPI 2: f32 out = c + res ; EPI 3: qkv + fused V^T
template <int MT, int NT, int EPI, bool SWAP, int WPB>
__global__ __launch_bounds__(256, WPB)
void gemm_pl(const __bf16* __restrict__ A, const __bf16* __restrict__ BT,
             const float* __restrict__ bias, const float* __restrict__ res,
             void* __restrict__ outv, __bf16* __restrict__ vtb,
             int M, int N, int K,
             const float* __restrict__ c0p, const float* __restrict__ c1p,
             const float* __restrict__ c2p) {
  // unpadded 64B rows for glds; 16B chunks XOR-swizzled by (row&3):
  // b128 fragment reads spread across banks (2-way max = free).
  __shared__ __bf16 As[3][MT][32];
  __shared__ __bf16 Bs[3][NT][32];
  constexpr int IW = MT / 32, JW = NT / 32;
  constexpr int S = MT / 64 + NT / 64;  // glds per wave per stage
  const int tid = threadIdx.x, lane = tid & 63, wid = tid >> 6;
  const int wr = wid >> 1, wc = wid & 1;
  const int mr = lane & 15, quad = lane >> 4;
  const int bx = SWAP ? blockIdx.y : blockIdx.x;
  const int by = SWAP ? blockIdx.x : blockIdx.y;
  const int m0 = by * MT, n0 = bx * NT;
  const int swzsrc = (((lane & 3) ^ ((lane >> 2) & 3)) * 8);
  const int srow = lane >> 2;
  const int ck = ((quad ^ (mr & 3)) * 8);

  f32x4 acc[IW][JW] = {};

  auto stage = [&](int k0, int buf) {
    for (int g = 0; g < MT / 64; g++) {
      int r0 = wid * (MT / 4) + g * 16 + srow;
      gl2lds16(&A[(size_t)(m0 + r0) * K + k0 + swzsrc], &As[buf][r0][(lane & 3) * 8]);
    }
    for (int g = 0; g < NT / 64; g++) {
      int r0 = wid * (NT / 4) + g * 16 + srow;
      gl2lds16(&BT[(size_t)(n0 + r0) * K + k0 + swzsrc], &Bs[buf][r0][(lane & 3) * 8]);
    }
  };

  const int T = K / 32;
  stage(0, 0);
  stage(32, 1);
  for (int it = 0; it < T; it++) {
    // need buf[it] ready; leave the newest stage in flight (tail: drain all)
    if (it < T - 1) pipe_barrier<S>(); else pipe_barrier<0>();
    if (it + 2 < T) stage((it + 2) * 32, (it + 2) % 3);
    const int pb = it % 3;
    bf16x8 af[IW], bfr[JW];
    for (int i = 0; i < IW; i++) af[i] = *(bf16x8*)&As[pb][wr * (MT / 2) + i * 16 + mr][ck];
    for (int j = 0; j < JW; j++) bfr[j] = *(bf16x8*)&Bs[pb][wc * (NT / 2) + j * 16 + mr][ck];
    for (int i = 0; i < IW; i++)
      for (int j = 0; j < JW; j++)
        acc[i][j] = __builtin_amdgcn_mfma_f32_16x16x32_bf16(af[i], bfr[j], acc[i][j], 0, 0, 0);
  }

  float ga = 0.f, gb = 0.f, gc = 0.f;
  if (EPI == 1) { ga = *c0p; gb = *c1p; gc = *c2p; }

  for (int i = 0; i < IW; i++) {
    for (int j = 0; j < JW; j++) {
      int col = n0 + wc * (NT / 2) + j * 16 + mr;
      float bv = bias[col];
      int row0 = m0 + wr * (MT / 2) + i * 16 + quad * 4;
      if (EPI == 3 && col >= 1536) {
        // V-part: write directly into V^T[(b*12+h)*64+d][token], 4 tokens/lane
        int hh = (col >> 6) - 24, dd = col & 63;
        bf16x4 pk;
        for (int r = 0; r < 4; r++) pk[r] = (__bf16)(acc[i][j][r] + bv);
        *(bf16x4*)&vtb[(((size_t)(row0 >> 11) * 12 + hh) * 64 + dd) * 2048 +
                       (row0 & 2047)] = pk;
      } else {
        for (int r = 0; r < 4; r++) {
          size_t idx = (size_t)(row0 + r) * N + col;
          float c = acc[i][j][r] + bv;
          if (EPI == 1) {
            float u = (ga * c + gb) * c + gc;
            ((__bf16*)outv)[idx] = (__bf16)u;
          } else if (EPI == 2) {
            ((float*)outv)[idx] = c + res[idx];
          } else {
            ((__bf16*)outv)[idx] = (__bf16)c;
          }
        }
      }
    }
  }
}

// -------- flash-style polynomial attention (R7 structure, unchanged) --------
__global__ __launch_bounds__(256, 3) void attn_poly(const __bf16* __restrict__ qkv,
                                                    const __bf16* __restrict__ vt,
                                                    __bf16* __restrict__ outp,
                                                    const float* __restrict__ ap,
                                                    const float* __restrict__ bp,
                                                    const float* __restrict__ cp) {
  __shared__ __bf16 Ps[4][32][72];   // 18,432 B (per-wave regions, padded)
  __shared__ __bf16 Kb[2][64][64];   // 16,384 B (unpadded, swizzled chunks)
  __shared__ __bf16 Vb[2][64][64];   // 16,384 B

  const int tid = threadIdx.x, lane = tid & 63, wid = tid >> 6;
  const int mr = lane & 15, quad = lane >> 4;
  const int q0 = blockIdx.x * 128;
  const int h = blockIdx.y, b = blockIdx.z;
  const int bh = b * 12 + h;
  const size_t baseQ = ((size_t)b * 2048) * 2304 + h * 64;

  const int swzsrc = (((lane & 7) ^ ((lane >> 3) & 7)) * 8);
  const int srow8 = lane >> 3;
  const int colS0 = ((quad ^ (mr & 7)) * 8);
  const int colS1 = (((4 + quad) ^ (mr & 7)) * 8);

  bf16x8 qf[2][2];
  for (int i = 0; i < 2; i++)
    for (int s = 0; s < 2; s++)
      qf[i][s] = *(const bf16x8*)&qkv[baseQ + (size_t)(q0 + wid * 32 + i * 16 + mr) * 2304 +
                                      s * 32 + quad * 8];

  const float a2 = (*ap) * 0.015625f, b2 = (*bp) * 0.125f, cc = *cp;
  f32x4 o_acc[2][4] = {};
  float l_acc[2] = {0.f, 0.f};

  auto stage = [&](int kt, int pb) {
    for (int g = 0; g < 2; g++) {
      int r0 = wid * 16 + g * 8 + srow8;
      gl2lds16(&qkv[baseQ + (size_t)(kt * 64 + r0) * 2304 + 768 + swzsrc],
               &Kb[pb][r0][(lane & 7) * 8]);
      gl2lds16(&vt[((size_t)bh * 64 + r0) * 2048 + kt * 64 + swzsrc],
               &Vb[pb][r0][(lane & 7) * 8]);
    }
  };

  stage(0, 0);
  int pb = 0;
  for (int kt = 0; kt < 32; kt++) {
    __syncthreads();
    if (kt < 31) stage(kt + 1, pb ^ 1);

    f32x4 sacc[2][4] = {};
    for (int j = 0; j < 4; j++) {
      for (int s = 0; s < 2; s++) {
        bf16x8 kf = *(bf16x8*)&Kb[pb][j * 16 + mr][s ? colS1 : colS0];
        for (int i = 0; i < 2; i++)
          sacc[i][j] = __builtin_amdgcn_mfma_f32_16x16x32_bf16(kf, qf[i][s], sacc[i][j], 0, 0, 0);
      }
    }
    for (int i = 0; i < 2; i++) {
      f32x4 racc = {0.f, 0.f, 0.f, 0.f};
      for (int j = 0; j < 4; j++) {
        f32x4 S = sacc[i][j];
        f32x4 p = (a2 * S + b2) * S + cc;
        p[0] = fmaxf(p[0], 1e-6f); p[1] = fmaxf(p[1], 1e-6f);
        p[2] = fmaxf(p[2], 1e-6f); p[3] = fmaxf(p[3], 1e-6f);
        racc += p;
        bf16x4 pk = {(__bf16)p[0], (__bf16)p[1], (__bf16)p[2], (__bf16)p[3]};
        *(bf16x4*)&Ps[wid][i * 16 + mr][j * 16 + quad * 4] = pk;
      }
      float rsum = racc[0] + racc[1] + racc[2] + racc[3];
      rsum += __shfl_xor(rsum, 16, 64);
      rsum += __shfl_xor(rsum, 32, 64);
      l_acc[i] += rsum;
    }

    __asm__ __volatile__("s_waitcnt lgkmcnt(0)" ::: "memory");

    for (int s = 0; s < 2; s++) {
      bf16x8 pf[2];
      for (int i = 0; i < 2; i++)
        pf[i] = *(bf16x8*)&Ps[wid][i * 16 + mr][s * 32 + quad * 8];
      for (int dt = 0; dt < 4; dt++) {
        bf16x8 vf = *(bf16x8*)&Vb[pb][dt * 16 + mr][s ? colS1 : colS0];
        for (int i = 0; i < 2; i++)
          o_acc[i][dt] = __builtin_amdgcn_mfma_f32_16x16x32_bf16(pf[i], vf, o_acc[i][dt], 0, 0, 0);
      }
    }
    __asm__ __volatile__("" ::: "memory");
    pb ^= 1;
  }

  size_t baseO = ((size_t)b * 2048) * 768 + h * 64;
  for (int i = 0; i < 2; i++) {
    float inv[4];
    for (int r = 0; r < 4; r++)
      inv[r] = 1.0f / (__shfl(l_acc[i], quad * 4 + r, 64) + 1e-8f);
    for (int dt = 0; dt < 4; dt++) {
      int q = q0 + wid * 32 + i * 16 + quad * 4;
      for (int r = 0; r < 4; r++)
        outp[baseO + (size_t)(q + r) * 768 + dt * 16 + mr] =
            (__bf16)(o_acc[i][dt][r] * inv[r]);
    }
  }
}

extern "C" void kernel_launch(void* const* d_in, const int* in_sizes, int n_in,
                              void* d_out, int out_size, void* d_ws, size_t ws_size,
                              hipStream_t stream) {
  const float* x     = (const float*)d_in[0];
  const float* ln1g  = (const float*)d_in[1];
  const float* ln1b  = (const float*)d_in[2];
  const float* ln2g  = (const float*)d_in[3];
  const float* ln2b  = (const float*)d_in[4];
  const float* qkvw  = (const float*)d_in[5];
  const float* qkvb  = (const float*)d_in[6];
  const float* projw = (const float*)d_in[7];
  const float* projb = (const float*)d_in[8];
  const float* fc1w  = (const float*)d_in[9];
  const float* fc1b  = (const float*)d_in[10];
  const float* fc2w  = (const float*)d_in[11];
  const float* fc2b  = (const float*)d_in[12];
  const float* attna = (const float*)d_in[13];
  const float* attnb = (const float*)d_in[14];
  const float* attnc = (const float*)d_in[15];
  const float* gelua = (const float*)d_in[16];
  const float* gelub = (const float*)d_in[17];
  const float* geluc = (const float*)d_in[18];

  char* ws = (char*)d_ws;
  __bf16* wT_qkv  = (__bf16*)(ws);             // [2304][768]  3,538,944 B
  __bf16* wT_proj = (__bf16*)(ws + 3538944);   // [768][768]   1,179,648 B
  __bf16* wT_fc1  = (__bf16*)(ws + 4718592);   // [3072][768]  4,718,592 B
  __bf16* wT_fc2  = (__bf16*)(ws + 9437184);   // [768][3072]  4,718,592 B
  __bf16* h       = (__bf16*)(ws + 14155776);  // [8192][768]  bf16 12,582,912 B
  float*  x1      = (float*)(ws + 26738688);   // [8192][768]  f32  25,165,824 B
  __bf16* qkvbuf  = (__bf16*)(ws + 51904512);  // [8192][2304] bf16 (dead after attn)
  __bf16* u       = (__bf16*)(ws + 51904512);  // [8192][3072] bf16 (overlaps qkv)
  __bf16* vtbuf   = (__bf16*)(ws + 89653248);  // [3072][2048] bf16 (live qkv->attn only)
  float*  outp    = (float*)d_out;

  transpose_k<<<dim3(2304 / 32, 768 / 32), 256, 0, stream>>>(qkvw, wT_qkv, 768, 2304);
  transpose_k<<<dim3(768 / 32, 768 / 32), 256, 0, stream>>>(projw, wT_proj, 768, 768);
  transpose_k<<<dim3(3072 / 32, 768 / 32), 256, 0, stream>>>(fc1w, wT_fc1, 768, 3072);
  transpose_k<<<dim3(768 / 32, 3072 / 32), 256, 0, stream>>>(fc2w, wT_fc2, 3072, 768);

  ln_kernel<<<8192, 256, 0, stream>>>(x, ln1g, ln1b, h);
  // qkv GEMM with fused V^T epilogue (writes Q|K to qkvbuf, V^T to vtbuf)
  gemm_pl<128, 128, 3, false, 3><<<dim3(18, 64), 256, 0, stream>>>(
      h, wT_qkv, qkvb, nullptr, qkvbuf, vtbuf, 8192, 2304, 768, nullptr, nullptr, nullptr);
  attn_poly<<<dim3(16, 12, 4), 256, 0, stream>>>(qkvbuf, vtbuf, h, attna, attnb, attnc);
  // proj (+x residual) -> x1 f32 ; grid swapped: consecutive blocks share B-panel
  gemm_pl<64, 128, 2, true, 4><<<dim3(128, 6), 256, 0, stream>>>(
      h, wT_proj, projb, x, x1, nullptr, 8192, 768, 768, nullptr, nullptr, nullptr);
  ln_kernel<<<8192, 256, 0, stream>>>(x1, ln2g, ln2b, h);
  gemm_pl<128, 128, 1, false, 3><<<dim3(24, 64), 256, 0, stream>>>(
      h, wT_fc1, fc1b, nullptr, u, nullptr, 8192, 3072, 768, gelua, gelub, geluc);
  gemm_pl<64, 128, 2, true, 4><<<dim3(128, 6), 256, 0, stream>>>(
      u, wT_fc2, fc2b, x1, outp, nullptr, 8192, 768, 3072, nullptr, nullptr, nullptr);
}